// Round 1
// baseline (410.909 us; speedup 1.0000x reference)
//
#include <hip/hip_runtime.h>
#include <math.h>

#define M   24
#define TS  60
#define NX  192
#define NY  192
#define H_  4
#define D_  8
#define NTS 50   // N_TIME_STEPS
#define NG  50

// Setup results computed by prep_kernel each call (always fully rewritten —
// no cross-call state dependence).
__device__ float g_w[M];
__device__ int   g_ti[NTS][M];
__device__ int   g_ix[NG];
__device__ float g_fx[NG];
__device__ float g_mx[NG];
__device__ int   g_iy[M][NG];
__device__ float g_fy[M][NG];
__device__ float g_my[M][NG];

__global__ __launch_bounds__(256) void prep_kernel(
    const float* __restrict__ params, const float* __restrict__ src_y,
    const float* __restrict__ stl,
    const float* __restrict__ Wq, const float* __restrict__ bq,
    const float* __restrict__ Wk, const float* __restrict__ bk,
    const float* __restrict__ lyt_p, const float* __restrict__ ccu_p,
    const float* __restrict__ cni_p)
{
    const int tid = threadIdx.x;
    __shared__ float s_logits[M][H_];
    __shared__ float s_sw[M];

    const float ly_target = lyt_p[0];
    const float c_cu_t = ccu_p[0];
    const float c_ni_t = cni_p[0];

    const float t_ly = (ly_target - 30.0f) / 90.0f;
    const float t_cu = c_cu_t / 0.0029f;
    const float t_ni = c_ni_t / 0.0018f;

    // ---- per-m logits + similarity weight ----
    if (tid < M) {
        const int m = tid;
        const float ly  = params[m*3 + 0];
        const float ccu = params[m*3 + 1];
        const float cni = params[m*3 + 2];
        const float ly_n = (ly - 30.0f) / 90.0f;
        const float cu_n = ccu / 0.0029f;
        const float ni_n = cni / 0.0018f;
        for (int h = 0; h < H_; ++h) {
            float acc = 0.0f;
            for (int d = 0; d < D_; ++d) {
                const int col = h*D_ + d;
                const float q = t_ly*Wq[0*32+col] + t_cu*Wq[1*32+col] + t_ni*Wq[2*32+col] + bq[col];
                const float k = ly_n*Wk[0*32+col] + cu_n*Wk[1*32+col] + ni_n*Wk[2*32+col] + bk[col];
                acc += k * q;
            }
            s_logits[m][h] = acc / sqrtf(8.0f);
        }
        const float dly = ly_n - t_ly, dcu = cu_n - t_cu, dni = ni_n - t_ni;
        const float d2 = (dly*dly + dcu*dcu + dni*dni) / 0.04f;
        s_sw[m] = expf(-d2 * 0.5f);
    }
    __syncthreads();

    if (tid == 0) {
        float attn[M];
        for (int m = 0; m < M; ++m) attn[m] = 0.0f;
        for (int h = 0; h < H_; ++h) {
            float mxv = -1e30f;
            for (int m = 0; m < M; ++m) mxv = fmaxf(mxv, s_logits[m][h]);
            float e[M]; float s = 0.0f;
            for (int m = 0; m < M; ++m) { e[m] = expf(s_logits[m][h] - mxv); s += e[m]; }
            for (int m = 0; m < M; ++m) attn[m] += e[m] / s;
        }
        float ssw = 0.0f;
        for (int m = 0; m < M; ++m) ssw += s_sw[m];
        float w[M]; float wsum = 0.0f;
        for (int m = 0; m < M; ++m) {
            w[m] = (attn[m] * 0.25f) * (s_sw[m] / (ssw + 1e-12f));
            wsum += w[m];
        }
        for (int m = 0; m < M; ++m) g_w[m] = w[m] / (wsum + 1e-12f);
    }

    // ---- ti[t][m] : banker's rounding to match jnp.round ----
    const float step_t = 200.0f / 49.0f;
    for (int idx = tid; idx < NTS*M; idx += blockDim.x) {
        const int t = idx / M, m = idx % M;
        const float tt = (t == NTS-1) ? 200.0f : step_t * (float)t;
        const float r = tt / stl[m] * 59.0f;
        int ti = (int)rintf(r);
        ti = ti < 0 ? 0 : (ti > TS-1 ? TS-1 : ti);
        g_ti[t][m] = ti;
    }

    // ---- x-axis interp setup (grid = linspace(0,100,192), q = linspace(0,100,50)) ----
    if (tid < NG) {
        const int i = tid;
        const float step_x = 100.0f / 191.0f;
        const float step_q = 100.0f / 49.0f;
        const float q = (i == NG-1) ? 100.0f : step_q * (float)i;
        int pos = 0;  // searchsorted(grid, q, 'right')
        for (int g = 0; g < NX; ++g) {
            const float gv = (g == NX-1) ? 100.0f : step_x * (float)g;
            if (gv <= q) pos = g + 1;
        }
        int id = pos - 1;
        id = id < 0 ? 0 : (id > NX-2 ? NX-2 : id);
        const float g0 = (id   == NX-1) ? 100.0f : step_x * (float)id;
        const float g1 = (id+1 == NX-1) ? 100.0f : step_x * (float)(id+1);
        g_ix[i] = id;
        g_fx[i] = (q - g0) / (g1 - g0);
        g_mx[i] = (q >= 0.0f && q <= 100.0f) ? 1.0f : 0.0f;
    }

    // ---- y-axis interp setup per m (grid = src_y[m,:] * (ly_target/lys[m])) ----
    for (int idx = tid; idx < M*NG; idx += blockDim.x) {
        const int m = idx / NG, j = idx % NG;
        const float scale = ly_target / params[m*3 + 0];   // IEEE fp32 div, matches ref
        const float q = (float)j / 49.0f * ly_target;
        const float* sy = src_y + m*NY;
        int pos = 0;
        for (int g = 0; g < NY; ++g) {
            const float gv = sy[g] * scale;                // IEEE fp32 mul, matches ref
            if (gv <= q) pos = g + 1;
        }
        int id = pos - 1;
        id = id < 0 ? 0 : (id > NY-2 ? NY-2 : id);
        const float g0 = sy[id] * scale;
        const float g1 = sy[id+1] * scale;
        g_iy[m][j] = id;
        g_fy[m][j] = (q - g0) / (g1 - g0);
        const float gfirst = sy[0] * scale;
        const float glast  = sy[NY-1] * scale;
        g_my[m][j] = (q >= gfirst && q <= glast) ? 1.0f : 0.0f;
    }
}

__global__ __launch_bounds__(256) void interp_kernel(
    const float* __restrict__ c1, const float* __restrict__ c2,
    float* __restrict__ out,
    const float* __restrict__ ccu_p, const float* __restrict__ cni_p)
{
    const int p = blockIdx.x * blockDim.x + threadIdx.x;
    if (p >= NG*NG) return;
    const int t = blockIdx.y;
    const int f = blockIdx.z;
    const int i = p / NG;
    const int j = p % NG;

    const float* __restrict__ preds = (f == 0) ? c1 : c2;

    const int   ixi = g_ix[i];
    const float fxi = g_fx[i];
    const float mxi = g_mx[i];

    float acc = 0.0f;
    #pragma unroll 4
    for (int m = 0; m < M; ++m) {
        const int tim   = g_ti[t][m];
        const int iyj   = g_iy[m][j];
        const float fyj = g_fy[m][j];
        const float msk = mxi * g_my[m][j];
        const float wm  = g_w[m];
        const float* base = preds + (((size_t)m*TS + tim)*NX + ixi)*(size_t)NY + iyj;
        const float v00 = base[0];
        const float v01 = base[1];
        const float v10 = base[NY];
        const float v11 = base[NY + 1];
        const float vx0 = v00*(1.0f - fxi) + v10*fxi;
        const float vx1 = v01*(1.0f - fxi) + v11*fxi;
        const float v   = (vx0*(1.0f - fyj) + vx1*fyj) * msk;
        acc += v * wm;
    }

    if (f == 0 && j == 0)    acc = ccu_p[0];
    if (f == 1 && j == NG-1) acc = cni_p[0];

    out[(((size_t)f*NTS + t)*NG + i)*NG + j] = acc;
}

extern "C" void kernel_launch(void* const* d_in, const int* in_sizes, int n_in,
                              void* d_out, int out_size, void* d_ws, size_t ws_size,
                              hipStream_t stream) {
    const float* c1     = (const float*)d_in[0];
    const float* c2     = (const float*)d_in[1];
    const float* params = (const float*)d_in[2];
    const float* src_y  = (const float*)d_in[3];
    const float* stl    = (const float*)d_in[4];
    const float* Wq     = (const float*)d_in[5];
    const float* bq     = (const float*)d_in[6];
    const float* Wk     = (const float*)d_in[7];
    const float* bk     = (const float*)d_in[8];
    const float* lyt    = (const float*)d_in[9];
    const float* ccut   = (const float*)d_in[10];
    const float* cnit   = (const float*)d_in[11];
    float* out = (float*)d_out;

    prep_kernel<<<1, 256, 0, stream>>>(params, src_y, stl, Wq, bq, Wk, bk, lyt, ccut, cnit);

    dim3 grid((NG*NG + 255) / 256, NTS, 2);
    interp_kernel<<<grid, 256, 0, stream>>>(c1, c2, out, ccut, cnit);
}